// Round 6
// baseline (287.722 us; speedup 1.0000x reference)
//
#include <hip/hip_runtime.h>
#include <math.h>

#define HIDDEN 1024
#define INTER  1408
#define NEXP   8
#define NTOK   2048
#define KSPLIT_LEN 704   // INTER/2

typedef short s16x8 __attribute__((ext_vector_type(8)));   // 8 bf16 MFMA operand
typedef float f32x4 __attribute__((ext_vector_type(4)));   // MFMA accumulator

static __device__ __forceinline__ short f2b(float f) {
  union { float f; unsigned u; } v; v.f = f;
  unsigned u = v.u;
  unsigned r = (u + 0x7FFFu + ((u >> 16) & 1u)) >> 16;   // RNE
  return (short)r;
}

// ---------------------------------------------------------------------------
// Fused prep, one flat grid of 256-thread blocks:
//   [0, 512)      router choice: one wave per token, fp32 exact, no atomics.
//                 writes ce[t] = e0|e1<<8, cw[t] = (w0,w1)
//   [512, 1536)   x fp32 -> bf16 streaming copy
//   [1536, ...)   weight transpose-convert fp32 [e][K][N] -> bf16 [e][N][K],
//                 REGISTER transpose (no LDS): block = 64k x 128n tile,
//                 thread = (one n column, one 32-row k-half). Reads: full
//                 128B lines (2 rows x 32 cols per instr). Writes: lane pairs
//                 fill 128B output lines. 32 independent loads/thread.
// ---------------------------------------------------------------------------
__global__ __launch_bounds__(256) void prep_kernel(
    const float* __restrict__ x, const float* __restrict__ rw,
    const float* __restrict__ wg, const float* __restrict__ wu,
    const float* __restrict__ wd,
    int* __restrict__ ce, float2* __restrict__ cw,
    short* __restrict__ xb, short* __restrict__ wgT,
    short* __restrict__ wuT, short* __restrict__ wdT)
{
  int id = blockIdx.x;
  int tid = threadIdx.x;

  if (id < 512) {
    // ---- router choice ----
    int wave = tid >> 6;
    int lane = tid & 63;
    int t = id * 4 + wave;
    const float* xt = x + (size_t)t * HIDDEN;
    float xr[16];
#pragma unroll
    for (int i = 0; i < 16; ++i) xr[i] = xt[lane + 64 * i];
    float logits[NEXP];
#pragma unroll
    for (int e = 0; e < NEXP; ++e) {
      const float* w = rw + e * HIDDEN;
      float acc = 0.f;
#pragma unroll
      for (int i = 0; i < 16; ++i) acc = fmaf(xr[i], w[lane + 64 * i], acc);
#pragma unroll
      for (int off = 32; off > 0; off >>= 1) acc += __shfl_xor(acc, off);
      logits[e] = acc;
    }
    if (lane == 0) {
      float mx = logits[0];
#pragma unroll
      for (int e = 1; e < NEXP; ++e) mx = fmaxf(mx, logits[e]);
      float p[NEXP];
#pragma unroll
      for (int e = 0; e < NEXP; ++e) p[e] = expf(logits[e] - mx);
      int i0 = 0;
#pragma unroll
      for (int e = 1; e < NEXP; ++e) if (p[e] > p[i0]) i0 = e;
      int i1 = (i0 == 0) ? 1 : 0;
#pragma unroll
      for (int e = 0; e < NEXP; ++e) { if (e != i0 && p[e] > p[i1]) i1 = e; }
      float denom = p[i0] + p[i1];
      ce[t] = i0 | (i1 << 8);
      cw[t] = make_float2(p[i0] / denom, p[i1] / denom);
    }
    return;
  }
  id -= 512;

  if (id < 1024) {
    // ---- x convert ----
    size_t i = (size_t)id * 256 + tid;
    const float4* p = (const float4*)x;
    float4 a = p[2 * i], b = p[2 * i + 1];
    s16x8 o;
    o[0] = f2b(a.x); o[1] = f2b(a.y); o[2] = f2b(a.z); o[3] = f2b(a.w);
    o[4] = f2b(b.x); o[5] = f2b(b.y); o[6] = f2b(b.z); o[7] = f2b(b.w);
    *(s16x8*)(xb + 8 * i) = o;
    return;
  }
  id -= 1024;

  // ---- weight transpose-convert ----
  int seg = id / 1408;          // 0: wg, 1: wu, 2: wd
  int r = id - seg * 1408;
  int e = r / 176;
  int rem = r - e * 176;
  int K, N;
  const float* ie;
  short* oe;
  if (seg < 2) {
    K = HIDDEN; N = INTER;
    ie = (seg == 0 ? wg : wu) + (size_t)e * HIDDEN * INTER;
    oe = (seg == 0 ? wgT : wuT) + (size_t)e * HIDDEN * INTER;
  } else {
    K = INTER; N = HIDDEN;
    ie = wd + (size_t)e * HIDDEN * INTER;
    oe = wdT + (size_t)e * HIDDEN * INTER;
  }
  int ntiles = N >> 7;                       // N/128
  int kt = rem / ntiles, nt = rem - kt * ntiles;
  int k0 = kt * 64, n0 = nt * 128;

  int n = n0 + (tid >> 1);
  int kh = (tid & 1) * 32;
  const float* ip = ie + (size_t)(k0 + kh) * N + n;

  float v[32];
#pragma unroll
  for (int j = 0; j < 32; ++j) v[j] = ip[(size_t)j * N];

  s16x8 o0, o1, o2, o3;
#pragma unroll
  for (int j = 0; j < 8; ++j) o0[j] = f2b(v[j]);
#pragma unroll
  for (int j = 0; j < 8; ++j) o1[j] = f2b(v[8 + j]);
#pragma unroll
  for (int j = 0; j < 8; ++j) o2[j] = f2b(v[16 + j]);
#pragma unroll
  for (int j = 0; j < 8; ++j) o3[j] = f2b(v[24 + j]);

  short* op = oe + (size_t)n * K + k0 + kh;
  *(s16x8*)(op)      = o0;
  *(s16x8*)(op + 8)  = o1;
  *(s16x8*)(op + 16) = o2;
  *(s16x8*)(op + 24) = o3;
}

// ---------------------------------------------------------------------------
// Router phase 2: one block per expert. Deterministic stable compaction via
// register histogram + LDS scan; also emits counts[e] and base[e].
// ---------------------------------------------------------------------------
__global__ __launch_bounds__(256) void build_lists(
    const int* __restrict__ ce, const float2* __restrict__ cw,
    int* __restrict__ counts, int* __restrict__ base,
    int* __restrict__ tok_list, float* __restrict__ w_list)
{
  int e = blockIdx.x;          // 0..7
  int tid = threadIdx.x;       // each thread owns tokens [8*tid, 8*tid+8)
  __shared__ int hall[256][8];
  __shared__ int hsum[8];
  __shared__ int scan[256];

  int cloc[8];
  int h[8] = {0,0,0,0,0,0,0,0};
  int myc = 0;
#pragma unroll
  for (int j = 0; j < 8; ++j) {
    int c = ce[tid * 8 + j];
    cloc[j] = c;
    int e0 = c & 255, e1 = (c >> 8) & 255;
    h[e0]++; h[e1]++;
    myc += (e0 == e) + (e1 == e);
  }
#pragma unroll
  for (int k = 0; k < 8; ++k) hall[tid][k] = h[k];
  scan[tid] = myc;
  __syncthreads();

  if (tid < 8) {
    int s = 0;
    for (int i = 0; i < 256; ++i) s += hall[i][tid];
    hsum[tid] = s;
  }
  int v = myc;
  for (int off = 1; off < 256; off <<= 1) {
    int prev = (tid >= off) ? scan[tid - off] : 0;
    __syncthreads();
    v = v + prev;
    scan[tid] = v;
    __syncthreads();
  }
  int pos = v - myc;

  if (tid == 0) {
    int b = 0;
    for (int k = 0; k < e; ++k) b += hsum[k];
    base[e] = b;
    counts[e] = hsum[e];
  }

#pragma unroll
  for (int j = 0; j < 8; ++j) {
    int t = tid * 8 + j;
    int c = cloc[j];
    int e0 = c & 255, e1 = (c >> 8) & 255;
    if (e0 == e) {
      float2 w = cw[t];
      tok_list[e * NTOK + pos] = t;                // slot 0
      w_list[e * NTOK + pos] = w.x;
      pos++;
    } else if (e1 == e) {
      float2 w = cw[t];
      tok_list[e * NTOK + pos] = t | (1 << 16);    // slot 1
      w_list[e * NTOK + pos] = w.y;
      pos++;
    }
  }
}

// ---------------------------------------------------------------------------
// Staging geometry (both GEMMs), XOR-swizzled LDS [row][4 chunks]:
//   phys chunk p of row r holds logical chunk p ^ ((r>>1)&3); fragment read
//   (lane ml, quad q) uses phys q ^ ((ml>>1)&3) -> 2-way aliasing only (free).
//   Measured 0 LDS bank conflicts (r3/r4).
// ---------------------------------------------------------------------------

// ---------------------------------------------------------------------------
// Phase A: H = silu(X@Wg)*(X@Wu). Tile M=128 N=128 BK=32, 4 waves (2x2),
// 4x4 MFMAs each for gate AND up; register prefetch issued after the
// LDS-ready barrier. XCD-swizzled flat grid for weight-strip L2 locality.
// ---------------------------------------------------------------------------
__global__ __launch_bounds__(256, 2) void gateup_mfma(
    const short* __restrict__ xb, const short* __restrict__ wgT,
    const short* __restrict__ wuT,
    const int* __restrict__ counts, const int* __restrict__ base,
    const int* __restrict__ tok_list, short* __restrict__ hbuf)
{
  // grid = 8 xcd * 16 m * 11 g-hi = 1408; g = (e,n) in 0..87
  int id = blockIdx.x;
  int xcd = id & 7;
  int rest = id >> 3;
  int mslot = rest & 15;
  int g = (rest >> 4) * 8 + xcd;
  int e = g / 11;
  int n0 = (g - e * 11) * 128;
  int cnt = counts[e];
  int m0 = mslot * 128;
  if (m0 >= cnt) return;

  __shared__ short As[128 * 32];
  __shared__ short Bg[128 * 32];
  __shared__ short Bu[128 * 32];
  __shared__ int toks[128];

  int tid = threadIdx.x;
  if (tid < 128) {
    int r = m0 + tid;
    toks[tid] = tok_list[e * NTOK + (r < cnt ? r : cnt - 1)] & 0xFFFF;
  }
  __syncthreads();

  int sr = tid >> 1;             // 0..127
  int h = tid & 1;
  int key = (sr >> 1) & 3;
  int pair = ((2 * h) ^ key) >> 1;           // which 32B global block
  int sw = (key & 1) * 8;                    // swap c0/c1 on write
  const short* gA = xb + (size_t)toks[sr] * HIDDEN + pair * 16;
  const short* gG = wgT + ((size_t)e * INTER + n0 + sr) * HIDDEN + pair * 16;
  const short* gU = wuT + ((size_t)e * INTER + n0 + sr) * HIDDEN + pair * 16;
  short* wA0 = &As[sr * 32 + h * 16 + sw];
  short* wA1 = &As[sr * 32 + h * 16 + (8 - sw)];
  short* wG0 = &Bg[sr * 32 + h * 16 + sw];
  short* wG1 = &Bg[sr * 32 + h * 16 + (8 - sw)];
  short* wU0 = &Bu[sr * 32 + h * 16 + sw];
  short* wU1 = &Bu[sr * 32 + h * 16 + (8 - sw)];

  int wv = tid >> 6, lane = tid & 63;
  int wm = wv & 1, wn = wv >> 1;
  int q = lane >> 4, ml = lane & 15;
  int chk = q ^ ((ml >> 1) & 3);
  const short* ard = &As[(wm * 64 + ml) * 32 + chk * 8];
  const short* grd = &Bg[(wn * 64 + ml) * 32 + chk * 8];
  const short* urd = &Bu[(wn * 64 + ml) * 32 + chk * 8];

  f32x4 accg[4][4], accu[4][4];
#pragma unroll
  for (int i = 0; i < 4; ++i)
#pragma unroll
    for (int j = 0; j < 4; ++j) { accg[i][j] = (f32x4)0.f; accu[i][j] = (f32x4)0.f; }

  s16x8 a0 = *(const s16x8*)(gA);     s16x8 a1 = *(const s16x8*)(gA + 8);
  s16x8 g0 = *(const s16x8*)(gG);     s16x8 g1 = *(const s16x8*)(gG + 8);
  s16x8 u0 = *(const s16x8*)(gU);     s16x8 u1 = *(const s16x8*)(gU + 8);

  for (int k0 = 0; k0 < HIDDEN; k0 += 32) {
    __syncthreads();
    *(s16x8*)wA0 = a0; *(s16x8*)wA1 = a1;
    *(s16x8*)wG0 = g0; *(s16x8*)wG1 = g1;
    *(s16x8*)wU0 = u0; *(s16x8*)wU1 = u1;
    __syncthreads();

    int kn = (k0 + 32) & (HIDDEN - 1);
    a0 = *(const s16x8*)(gA + kn);     a1 = *(const s16x8*)(gA + kn + 8);
    g0 = *(const s16x8*)(gG + kn);     g1 = *(const s16x8*)(gG + kn + 8);
    u0 = *(const s16x8*)(gU + kn);     u1 = *(const s16x8*)(gU + kn + 8);

    s16x8 af[4], gf[4], uf[4];
#pragma unroll
    for (int i = 0; i < 4; ++i) af[i] = *(const s16x8*)(ard + i * 16 * 32);
#pragma unroll
    for (int j = 0; j < 4; ++j) {
      gf[j] = *(const s16x8*)(grd + j * 16 * 32);
      uf[j] = *(const s16x8*)(urd + j * 16 * 32);
    }
#pragma unroll
    for (int i = 0; i < 4; ++i)
#pragma unroll
      for (int j = 0; j < 4; ++j) {
        accg[i][j] = __builtin_amdgcn_mfma_f32_16x16x32_bf16(af[i], gf[j], accg[i][j], 0, 0, 0);
        accu[i][j] = __builtin_amdgcn_mfma_f32_16x16x32_bf16(af[i], uf[j], accu[i][j], 0, 0, 0);
      }
  }

  int hb = base[e];
#pragma unroll
  for (int i = 0; i < 4; ++i)
#pragma unroll
    for (int ii = 0; ii < 4; ++ii) {
      int r = m0 + wm * 64 + i * 16 + q * 4 + ii;
      if (r < cnt) {
        short* hp = hbuf + (size_t)(hb + r) * INTER + n0 + wn * 64 + ml;
#pragma unroll
        for (int j = 0; j < 4; ++j) {
          float gg = accg[i][j][ii], uu = accu[i][j][ii];
          float hh = (gg / (1.f + __expf(-gg))) * uu;
          hp[j * 16] = f2b(hh);
        }
      }
    }
}

// ---------------------------------------------------------------------------
// Phase B: Y = H @ Wd, K-split x2; scaled partials to ybuf[slot*2+ks][token]
// with plain stores (no atomics).
// ---------------------------------------------------------------------------
__global__ __launch_bounds__(256, 3) void down_mfma(
    const short* __restrict__ hbuf, const short* __restrict__ wdT,
    const int* __restrict__ counts, const int* __restrict__ base,
    const int* __restrict__ tok_list, const float* __restrict__ w_list,
    float* __restrict__ ybuf)
{
  // grid = 8 xcd * 16 m * 16 g-hi = 2048; g = (e,ks,n) in 0..127
  int id = blockIdx.x;
  int xcd = id & 7;
  int rest = id >> 3;
  int mslot = rest & 15;
  int g = (rest >> 4) * 8 + xcd;
  int e = g >> 4;
  int ks = (g >> 3) & 1;
  int n0 = (g & 7) * 128;
  int cnt = counts[e];
  int m0 = mslot * 128;
  if (m0 >= cnt) return;

  __shared__ short As[128 * 32];
  __shared__ short Bs[128 * 32];

  int tid = threadIdx.x;
  int hb = base[e];
  int kbeg = ks * KSPLIT_LEN, kend = kbeg + KSPLIT_LEN;

  int sr = tid >> 1;
  int h = tid & 1;
  int key = (sr >> 1) & 3;
  int pair = ((2 * h) ^ key) >> 1;
  int sw = (key & 1) * 8;
  int ra = m0 + sr; if (ra >= cnt) ra = cnt - 1;
  const short* gA = hbuf + (size_t)(hb + ra) * INTER + pair * 16;
  const short* gB = wdT + ((size_t)e * HIDDEN + n0 + sr) * INTER + pair * 16;
  short* wA0 = &As[sr * 32 + h * 16 + sw];
  short* wA1 = &As[sr * 32 + h * 16 + (8 - sw)];
  short* wB0 = &Bs[sr * 32 + h * 16 + sw];
  short* wB1 = &Bs[sr * 32 + h * 16 + (8 - sw)];

  int wv = tid >> 6, lane = tid & 63;
  int wm = wv & 1, wn = wv >> 1;
  int q = lane >> 4, ml = lane & 15;
  int chk = q ^ ((ml >> 1) & 3);
  const short* ard = &As[(wm * 64 + ml) * 32 + chk * 8];
  const short* brd = &Bs[(wn * 64 + ml) * 32 + chk * 8];

  f32x4 acc[4][4];
#pragma unroll
  for (int i = 0; i < 4; ++i)
#pragma unroll
    for (int j = 0; j < 4; ++j) acc[i][j] = (f32x4)0.f;

  s16x8 a0 = *(const s16x8*)(gA + kbeg);  s16x8 a1 = *(const s16x8*)(gA + kbeg + 8);
  s16x8 b0 = *(const s16x8*)(gB + kbeg);  s16x8 b1 = *(const s16x8*)(gB + kbeg + 8);

  for (int k0 = kbeg; k0 < kend; k0 += 32) {
    __syncthreads();
    *(s16x8*)wA0 = a0; *(s16x8*)wA1 = a1;
    *(s16x8*)wB0 = b0; *(s16x8*)wB1 = b1;
    __syncthreads();

    int kn = k0 + 32; if (kn >= kend) kn = kbeg;
    a0 = *(const s16x8*)(gA + kn);  a1 = *(const s16x8*)(gA + kn + 8);
    b0 = *(const s16x8*)(gB + kn);  b1 = *(const s16x8*)(gB + kn + 8);

    s16x8 af[4], bf[4];
#pragma unroll
    for (int i = 0; i < 4; ++i) af[i] = *(const s16x8*)(ard + i * 16 * 32);
#pragma unroll
    for (int j = 0; j < 4; ++j) bf[j] = *(const s16x8*)(brd + j * 16 * 32);
#pragma unroll
    for (int i = 0; i < 4; ++i)
#pragma unroll
      for (int j = 0; j < 4; ++j)
        acc[i][j] = __builtin_amdgcn_mfma_f32_16x16x32_bf16(af[i], bf[j], acc[i][j], 0, 0, 0);
  }

#pragma unroll
  for (int i = 0; i < 4; ++i)
#pragma unroll
    for (int ii = 0; ii < 4; ++ii) {
      int r = m0 + wm * 64 + i * 16 + q * 4 + ii;
      if (r < cnt) {
        int ent = tok_list[e * NTOK + r];
        int tok = ent & 0xFFFF, slot = ent >> 16;
        float wgt = w_list[e * NTOK + r];
        float* yp = ybuf + ((size_t)(slot * 2 + ks) * NTOK + tok) * HIDDEN
                    + n0 + wn * 64 + ml;
#pragma unroll
        for (int j = 0; j < 4; ++j)
          yp[j * 16] = acc[i][j][ii] * wgt;
      }
    }
}

// ---------------------------------------------------------------------------
// out = sum of 4 ybuf slabs (every element written -> no out memset needed)
// ---------------------------------------------------------------------------
__global__ __launch_bounds__(256) void combine_kernel(
    const float* __restrict__ ybuf, float* __restrict__ out)
{
  size_t i = (size_t)blockIdx.x * 256 + threadIdx.x;
  const size_t S = (size_t)NTOK * HIDDEN / 4;
  float4 a = ((const float4*)ybuf)[i];
  float4 b = ((const float4*)ybuf)[i + S];
  float4 c = ((const float4*)ybuf)[i + 2 * S];
  float4 d = ((const float4*)ybuf)[i + 3 * S];
  float4 o;
  o.x = (a.x + b.x) + (c.x + d.x);
  o.y = (a.y + b.y) + (c.y + d.y);
  o.z = (a.z + b.z) + (c.z + d.z);
  o.w = (a.w + b.w) + (c.w + d.w);
  ((float4*)out)[i] = o;
}

// ---------------------------------------------------------------------------
// ws layout (bytes):
//   0..32           counts[8]
//   32..64          base[8]
//   64..65600       tok_list[8][2048]  (token | slot<<16)
//   65600..131136   w_list[8][2048]
//   131136..139328  ce[2048]
//   139328..155712  cw[2048] float2
//   155712          xb   bf16 [2048][1024]      (4 MB)
//   +4 MB           wgT  bf16 [8][1408][1024]   (23.07 MB) } ybuf[4] (32 MB
//   +23.07 MB       wuT  bf16 [8][1408][1024]   (23.07 MB) } fp32) aliases
//                                                          } wgT+wuT after
//                                                          } gateup completes
//   +23.07 MB       wdT  bf16 [8][1024][1408]
//   +23.07 MB       hbuf bf16 [4096][1408]      (11.5 MB)
//   total ~85.2 MB
// ---------------------------------------------------------------------------
extern "C" void kernel_launch(void* const* d_in, const int* in_sizes, int n_in,
                              void* d_out, int out_size, void* d_ws, size_t ws_size,
                              hipStream_t stream)
{
  const float* x  = (const float*)d_in[0];
  const float* rw = (const float*)d_in[1];
  const float* wg = (const float*)d_in[2];
  const float* wu = (const float*)d_in[3];
  const float* wd = (const float*)d_in[4];
  float* out = (float*)d_out;

  char* ws = (char*)d_ws;
  int*    counts   = (int*)(ws);
  int*    base     = (int*)(ws + 32);
  int*    tok_list = (int*)(ws + 64);
  float*  w_list   = (float*)(ws + 64 + NEXP * NTOK * 4);
  size_t off = 64 + 2 * (size_t)NEXP * NTOK * 4;
  int*    ce = (int*)(ws + off);     off += NTOK * 4;
  float2* cw = (float2*)(ws + off);  off += NTOK * 8;
  short* xb  = (short*)(ws + off);  off += (size_t)NTOK * HIDDEN * 2;
  short* wgT = (short*)(ws + off);  off += (size_t)NEXP * HIDDEN * INTER * 2;
  short* wuT = (short*)(ws + off);  off += (size_t)NEXP * HIDDEN * INTER * 2;
  short* wdT = (short*)(ws + off);  off += (size_t)NEXP * HIDDEN * INTER * 2;
  short* hbuf = (short*)(ws + off);
  float* ybuf = (float*)wgT;   // wgT+wuT dead after gateup; 32 MB fits in 46 MB

  // router (512) + convx (1024) + transpose (3*1408)
  prep_kernel<<<512 + 1024 + 3 * 1408, 256, 0, stream>>>(
      x, rw, wg, wu, wd, ce, cw, xb, wgT, wuT, wdT);
  build_lists<<<NEXP, 256, 0, stream>>>(ce, cw, counts, base, tok_list, w_list);

  gateup_mfma<<<8 * 16 * 11, 256, 0, stream>>>(xb, wgT, wuT, counts, base, tok_list, hbuf);
  down_mfma<<<8 * 16 * 16, 256, 0, stream>>>(hbuf, wdT, counts, base, tok_list, w_list, ybuf);

  combine_kernel<<<(NTOK * HIDDEN / 4) / 256, 256, 0, stream>>>(ybuf, out);
}